// Round 12
// baseline (26.234 us; speedup 1.0000x reference)
//
#include <hip/hip_runtime.h>
#include <hip/hip_bf16.h>

// Problem dims (fixed): n=128, d=256, ic=16, oc=16, r=10
// x:   [n, d, ic, r]  f32; w: [d, ic, oc, r] f32; out: [n, d, oc, r] f32
// out[n,d,oc,r] = log( sum_ic exp(x)*exp(w) ) - log( sum_ic exp(w) )
//
// v12: two kernels, zero __syncthreads in the hot kernel.
//  prep: wexp[d][ic][oc][r] bf16 (pre-transposed, padded rows of 12) + lcs
//        [d][oc*10+r] f32 into d_ws.
//  main: 4 INDEPENDENT waves / 256-thr block; wave = (d, 4n); lane = (n4,oc).
//        Wave stages its own exp(x) rows into wave-private LDS (same-wave
//        visibility: lgkmcnt only, no barrier); wexp read from global
//        (L1-hot, 16x24B contiguous per ic); each lane's 10 outputs are a
//        contiguous 40B run of the out row -> no transpose, no res staging.

using bf16 = __hip_bfloat16;

#define WEXP_BYTES_PER_D 6144            // 256 (ic,oc) * 12 bf16 * 2 B
#define LCS_OFF (256 * WEXP_BYTES_PER_D) // 1,572,864 B

__device__ __forceinline__ unsigned short bf16_bits(float f) {
    bf16 h = __float2bfloat16(f);
    return *reinterpret_cast<unsigned short*>(&h);
}

// ---------------- prep: exp(w) transposed + log-colsums ---------------------
__global__ __launch_bounds__(256) void prep_kernel(const float* __restrict__ w,
                                                   void* __restrict__ ws) {
    __shared__ float lexp[256 * 12];     // 12.3 KB, [icoc][12]
    const int d   = blockIdx.x;
    const int tid = threadIdx.x;         // = ic*16 + oc
    const float* wp = w + d * 2560 + (tid >> 4) * 160 + (tid & 15) * 10;

    float ev[10];
#pragma unroll
    for (int k = 0; k < 5; ++k) {
        float2 v = *reinterpret_cast<const float2*>(wp + 2 * k);
        ev[2 * k]     = __expf(v.x);
        ev[2 * k + 1] = __expf(v.y);
    }
    // global bf16 store (packed pairs): 20 B at d*6144 + tid*24
    {
        unsigned u[5];
#pragma unroll
        for (int k = 0; k < 5; ++k)
            u[k] = (unsigned)bf16_bits(ev[2 * k]) |
                   ((unsigned)bf16_bits(ev[2 * k + 1]) << 16);
        unsigned* gp = reinterpret_cast<unsigned*>(
            reinterpret_cast<char*>(ws) + d * WEXP_BYTES_PER_D + tid * 24);
        *reinterpret_cast<uint2*>(gp)     = make_uint2(u[0], u[1]);
        *reinterpret_cast<uint2*>(gp + 2) = make_uint2(u[2], u[3]);
        gp[4] = u[4];
    }
    // LDS f32 copy for column sums
    {
        float* lp = lexp + tid * 12;
        *reinterpret_cast<float4*>(lp)     = make_float4(ev[0], ev[1], ev[2], ev[3]);
        *reinterpret_cast<float4*>(lp + 4) = make_float4(ev[4], ev[5], ev[6], ev[7]);
        *reinterpret_cast<float2*>(lp + 8) = make_float2(ev[8], ev[9]);
    }
    __syncthreads();

    if (tid < 160) {
        const int oc = tid / 10, rr = tid - (tid / 10) * 10;
        float s = 0.f;
#pragma unroll
        for (int ic = 0; ic < 16; ++ic) s += lexp[(ic * 16 + oc) * 12 + rr];
        float* lcs = reinterpret_cast<float*>(reinterpret_cast<char*>(ws) + LCS_OFF);
        lcs[d * 160 + tid] = __logf(s);
    }
}

// ---------------- main: barrier-free, wave-autonomous ------------------------
__global__ __launch_bounds__(256, 6) void main_kernel(const float* __restrict__ x,
                                                      const void* __restrict__ ws,
                                                      float* __restrict__ out) {
    __shared__ float exs[4 * 784];       // 12.5 KB; 784 dwords per wave slice
    const int tid  = threadIdx.x;
    const int wid  = tid >> 6;
    const int lane = tid & 63;
    const int n4   = lane >> 4;          // 0..3
    const int oc   = lane & 15;          // compute oc == staging ic
    const int d    = blockIdx.x >> 3;
    const int nc   = blockIdx.x & 7;
    const int n    = nc * 16 + wid * 4 + n4;

    const float* xrow = x + (n * 256 + d) * 160;
    float* ebase = exs + wid * 784 + n4 * 196;

    // ---- stage exp(x[n][ic=oc][r0..9]) into wave-private LDS ---------------
    float ev[10];
#pragma unroll
    for (int k = 0; k < 5; ++k) {
        float2 v = *reinterpret_cast<const float2*>(xrow + oc * 10 + 2 * k);
        ev[2 * k]     = __expf(v.x);
        ev[2 * k + 1] = __expf(v.y);
    }
    {
        float* sp = ebase + oc * 12;
        *reinterpret_cast<float4*>(sp)     = make_float4(ev[0], ev[1], ev[2], ev[3]);
        *reinterpret_cast<float4*>(sp + 4) = make_float4(ev[4], ev[5], ev[6], ev[7]);
        *reinterpret_cast<float2*>(sp + 8) = make_float2(ev[8], ev[9]);
    }
    // lcs loads (L2-hot; independent of LDS)
    float lc[10];
    {
        const float* lp = reinterpret_cast<const float*>(
            reinterpret_cast<const char*>(ws) + LCS_OFF) + d * 160 + oc * 10;
#pragma unroll
        for (int k = 0; k < 5; ++k) {
            float2 v = *reinterpret_cast<const float2*>(lp + 2 * k);
            lc[2 * k] = v.x; lc[2 * k + 1] = v.y;
        }
    }
    // same-wave LDS visibility: wait own-wave LDS ops; NO s_barrier
    asm volatile("s_waitcnt lgkmcnt(0)" ::: "memory");

    // ---- accumulate over ic -------------------------------------------------
    float acc[10];
#pragma unroll
    for (int rr = 0; rr < 10; ++rr) acc[rr] = 0.f;

    const char* wb = reinterpret_cast<const char*>(ws) + d * WEXP_BYTES_PER_D + oc * 24;
#pragma unroll
    for (int ic = 0; ic < 16; ++ic) {
        const float* ep = ebase + ic * 12;
        const float4 e0 = *reinterpret_cast<const float4*>(ep);
        const float4 e1 = *reinterpret_cast<const float4*>(ep + 4);
        const float2 e2 = *reinterpret_cast<const float2*>(ep + 8);
        const unsigned* gp = reinterpret_cast<const unsigned*>(wb + ic * 384);
        const uint2 w01 = *reinterpret_cast<const uint2*>(gp);
        const uint2 w23 = *reinterpret_cast<const uint2*>(gp + 2);
        const unsigned w4 = gp[4];
        const float e[10] = {e0.x, e0.y, e0.z, e0.w, e1.x, e1.y, e1.z, e1.w, e2.x, e2.y};
        const float wv[10] = {
            __uint_as_float(w01.x << 16), __uint_as_float(w01.x & 0xFFFF0000u),
            __uint_as_float(w01.y << 16), __uint_as_float(w01.y & 0xFFFF0000u),
            __uint_as_float(w23.x << 16), __uint_as_float(w23.x & 0xFFFF0000u),
            __uint_as_float(w23.y << 16), __uint_as_float(w23.y & 0xFFFF0000u),
            __uint_as_float(w4 << 16),    __uint_as_float(w4 & 0xFFFF0000u)};
#pragma unroll
        for (int rr = 0; rr < 10; ++rr) acc[rr] = fmaf(e[rr], wv[rr], acc[rr]);
    }

    // ---- epilogue + store: lane owns a contiguous 40B run of the out row ---
    float* orow = out + (n * 256 + d) * 160 + oc * 10;
#pragma unroll
    for (int k = 0; k < 5; ++k) {
        float2 o;
        o.x = __logf(acc[2 * k])     - lc[2 * k];
        o.y = __logf(acc[2 * k + 1]) - lc[2 * k + 1];
        *reinterpret_cast<float2*>(orow + 2 * k) = o;
    }
}

extern "C" void kernel_launch(void* const* d_in, const int* in_sizes, int n_in,
                              void* d_out, int out_size, void* d_ws, size_t ws_size,
                              hipStream_t stream) {
    const float* x = (const float*)d_in[0];
    const float* w = (const float*)d_in[1];
    float* out = (float*)d_out;

    prep_kernel<<<256, 256, 0, stream>>>(w, d_ws);
    // grid: d = bid>>3 (256), nc = bid&7 (8 chunks of 16 n)
    main_kernel<<<2048, 256, 0, stream>>>(x, d_ws, out);
}

// Round 13
// 17.991 us; speedup vs baseline: 1.4582x; 1.4582x over previous
//
#include <hip/hip_runtime.h>
#include <hip/hip_bf16.h>

// Problem dims (fixed): n=128, d=256, ic=16, oc=16, r=10
// x:   [n, d, ic, r]  f32; w: [d, ic, oc, r] f32; out: [n, d, oc, r] f32
// out[n,d,oc,r] = log( sum_ic exp(x)*exp(w) ) - log( sum_ic exp(w) )
//
// v13: MFMA. Per (d,r) the reduction is a 128x16x16 GEMM ->
// mfma_f32_16x16x32_bf16, K zero-padded 16->32 (BOTH operands' slots
// 16..31 zeroed -> pad contributes 0 regardless of HW k-order; staging
// A and B by the SAME slot index makes the kernel invariant to the HW
// k-permutation). Block = one d-column: 256 blocks x 512 thr, 97 KB LDS,
// 2 barriers. No res-LDS: C-fragment rows give each lane 10 contiguous
// f32 per output row -> direct coalesced float2 stores.

typedef __attribute__((ext_vector_type(8))) short bf16x8;
typedef __attribute__((ext_vector_type(4))) float f32x4;

__device__ __forceinline__ unsigned short f2bf(float v) {
    // RNE bf16 (inputs are positive finite: exp() of |x|<~5.5)
    unsigned u = __float_as_uint(v);
    u += 0x7FFF + ((u >> 16) & 1);
    return (unsigned short)(u >> 16);
}

__global__ __launch_bounds__(512, 2) void fused_mfma_kernel(const float* __restrict__ x,
                                                            const float* __restrict__ w,
                                                            float* __restrict__ out) {
    // es[n=128][r=10][slot=32] bf16, row stride 328 shorts (656 B -> 2-way banks)
    __shared__ __align__(16) unsigned short es[128 * 328];   // 84.0 KB
    // ws[r=10][oc=16][slot=32] bf16, oc stride 40 shorts (80 B -> 2-way banks)
    __shared__ __align__(16) unsigned short ws_[10 * 640];   // 12.8 KB
    __shared__ float lcs[160];                               // lcs[oc*10+r]

    const int tid = threadIdx.x;
    const int d   = blockIdx.x;          // 0..255

    // ---- phase 1: stage everything ----------------------------------------
    {
        const int n_l = tid >> 2;        // 0..127
        const int seg = tid & 3;         // 0..3 (40 dwords each)
        const float* xg = x + (n_l * 256 + d) * 160 + seg * 40;
        float4 xv[10];
#pragma unroll
        for (int k = 0; k < 10; ++k) xv[k] = *reinterpret_cast<const float4*>(xg + 4 * k);
        const float* wgp = w + d * 2560 + tid * 5;
        float wv[5];
#pragma unroll
        for (int k = 0; k < 5; ++k) wv[k] = wgp[k];

        const float* xf = reinterpret_cast<const float*>(xv);
#pragma unroll
        for (int k = 0; k < 40; ++k) {
            const int icr = seg * 40 + k;           // = ic*10 + r
            const int ic  = icr / 10;
            const int r   = icr - ic * 10;
            es[n_l * 328 + r * 32 + ic] = f2bf(__expf(xf[k]));
        }
#pragma unroll
        for (int k = 0; k < 5; ++k) {
            const int off = tid * 5 + k;            // = ic*160 + oc*10 + r
            const int ic  = off / 160;
            const int rem = off - ic * 160;
            const int oc  = rem / 10;
            const int r   = rem - oc * 10;
            ws_[r * 640 + oc * 40 + ic] = f2bf(__expf(wv[k]));
        }
        // zero the pad slots 16..31 (both operands -> pad products are 0*0)
        const uint4 z = make_uint4(0u, 0u, 0u, 0u);
        for (int c = tid; c < 1280; c += 512) {     // es: (n, r) chunks
            const int n = c / 10, r = c - (c / 10) * 10;
            uint4* p = reinterpret_cast<uint4*>(&es[n * 328 + r * 32 + 16]);
            p[0] = z; p[1] = z;
        }
        if (tid < 160) {                            // ws: (r, oc) chunks
            const int r = tid >> 4, oc = tid & 15;
            uint4* p = reinterpret_cast<uint4*>(&ws_[r * 640 + oc * 40 + 16]);
            p[0] = z; p[1] = z;
        }
    }
    __syncthreads();

    // ---- phase 2: lcs (160 thr) + MFMAs (all waves) -------------------------
    if (tid < 160) {
        const int oc = tid / 10, r = tid - (tid / 10) * 10;
        const unsigned short* p = &ws_[r * 640 + oc * 40];
        float s = 0.f;
#pragma unroll
        for (int ic = 0; ic < 16; ++ic)
            s += __uint_as_float(((unsigned)p[ic]) << 16);
        lcs[oc * 10 + r] = __logf(s);
    }

    const int mt = tid >> 6;             // wave id = m-tile 0..7 (n0 = 16*mt)
    const int l  = tid & 63;
    const int lm = l & 15;               // A row within tile / B col (oc)
    const int kg = l >> 4;               // k-slot group 0..3

    const int abase = (mt * 16 + lm) * 328 + kg * 8;
    const int bbase = lm * 40 + kg * 8;

    f32x4 acc[10];
    const f32x4 zero = {0.f, 0.f, 0.f, 0.f};
#pragma unroll
    for (int r = 0; r < 10; ++r) {
        bf16x8 a = *reinterpret_cast<const bf16x8*>(&es[abase + r * 32]);
        bf16x8 b = *reinterpret_cast<const bf16x8*>(&ws_[r * 640 + bbase]);
        acc[r] = __builtin_amdgcn_mfma_f32_16x16x32_bf16(a, b, zero, 0, 0, 0);
    }
    __syncthreads();   // lcs visible

    // ---- phase 3: epilogue, direct coalesced stores -------------------------
    // C layout (m89): col = lane&15 (=oc), row = (lane>>4)*4 + j
    float lc[10];
#pragma unroll
    for (int r = 0; r < 10; ++r) lc[r] = lcs[lm * 10 + r];

#pragma unroll
    for (int j = 0; j < 4; ++j) {
        const int n = mt * 16 + kg * 4 + j;
        float* og = out + (n * 256 + d) * 160 + lm * 10;
#pragma unroll
        for (int h = 0; h < 5; ++h) {
            float2 o;
            o.x = __logf(acc[2 * h][j])     - lc[2 * h];
            o.y = __logf(acc[2 * h + 1][j]) - lc[2 * h + 1];
            *reinterpret_cast<float2*>(og + 2 * h) = o;
        }
    }
}

extern "C" void kernel_launch(void* const* d_in, const int* in_sizes, int n_in,
                              void* d_out, int out_size, void* d_ws, size_t ws_size,
                              hipStream_t stream) {
    const float* x = (const float*)d_in[0];
    const float* w = (const float*)d_in[1];
    float* out = (float*)d_out;

    // one block per d-column (all 128 n)
    fused_mfma_kernel<<<256, 512, 0, stream>>>(x, w, out);
}

// Round 14
// 16.652 us; speedup vs baseline: 1.5754x; 1.0804x over previous
//
#include <hip/hip_runtime.h>
#include <hip/hip_bf16.h>

// Problem dims (fixed): n=128, d=256, ic=16, oc=16, r=10
// x:   [n, d, ic, r]  f32; w: [d, ic, oc, r] f32; out: [n, d, oc, r] f32
// out[n,d,oc,r] = log( sum_ic exp(x)*exp(w) ) - log( sum_ic exp(w) )
//
// v14 = v13 (MFMA, K zero-padded 16->32, both operands slot-indexed so the
// HW k-permutation cancels; m89 C-layout verified in v13) with the block
// halved: (d, 64n), 256 threads, 54 KB LDS -> 2 blocks/CU (512 blocks),
// so load/store phases of co-resident blocks overlap. Staging writes
// packed: 20x ds_write_b64 per thread instead of 40x ds_write_b16.

typedef __attribute__((ext_vector_type(8))) short bf16x8;
typedef __attribute__((ext_vector_type(4))) float f32x4;

__device__ __forceinline__ unsigned short f2bf(float v) {
    unsigned u = __float_as_uint(v);
    u += 0x7FFF + ((u >> 16) & 1);
    return (unsigned short)(u >> 16);
}

__global__ __launch_bounds__(256, 2) void fused_mfma_kernel(const float* __restrict__ x,
                                                            const float* __restrict__ w,
                                                            float* __restrict__ out) {
    // es[n=64][r*32+slot] bf16, row stride 328 shorts (656B -> banks shift 4/row)
    __shared__ __align__(16) unsigned short es[64 * 328];    // 42.0 KB
    // ws[r=10][oc*40+slot] bf16
    __shared__ __align__(16) unsigned short ws_[10 * 640];   // 12.8 KB
    __shared__ float lcs[160];                                // lcs[oc*10+r]

    const int tid = threadIdx.x;
    const int d   = blockIdx.x & 255;
    const int nb  = (blockIdx.x >> 8) << 6;      // 0 or 64

    // ---- phase 1: stage x (packed b64 writes) + w + pad zeros ---------------
    {
        const int n_l = tid >> 2;                // 0..63
        const int seg = tid & 3;                 // 0..3 (40 dwords each)
        const float* xg = x + ((nb + n_l) * 256 + d) * 160 + seg * 40;
        float4 xv[10];
#pragma unroll
        for (int k = 0; k < 10; ++k) xv[k] = *reinterpret_cast<const float4*>(xg + 4 * k);

        const float* wgp = w + d * 2560 + tid * 10;
        float wv[10];
#pragma unroll
        for (int k = 0; k < 5; ++k) {
            float2 v = *reinterpret_cast<const float2*>(wgp + 2 * k);
            wv[2 * k] = v.x; wv[2 * k + 1] = v.y;
        }

        const float* xf = reinterpret_cast<const float*>(xv);
        // per r: pack bf16 of exp(xf[r]), exp(xf[10+r]), exp(xf[20+r]), exp(xf[30+r])
        //        -> es[n_l][r*32 + 4*seg .. +3]; zeros -> slots 16+4*seg .. +3
#pragma unroll
        for (int r = 0; r < 10; ++r) {
            unsigned short s0 = f2bf(__expf(xf[r]));
            unsigned short s1 = f2bf(__expf(xf[10 + r]));
            unsigned short s2 = f2bf(__expf(xf[20 + r]));
            unsigned short s3 = f2bf(__expf(xf[30 + r]));
            const unsigned lo = (unsigned)s0 | ((unsigned)s1 << 16);
            const unsigned hi = (unsigned)s2 | ((unsigned)s3 << 16);
            unsigned* dst = reinterpret_cast<unsigned*>(&es[n_l * 328 + r * 32 + 4 * seg]);
            *reinterpret_cast<uint2*>(dst) = make_uint2(lo, hi);
            unsigned* pad = reinterpret_cast<unsigned*>(&es[n_l * 328 + r * 32 + 16 + 4 * seg]);
            *reinterpret_cast<uint2*>(pad) = make_uint2(0u, 0u);
        }
        // w: 10 scattered b16 writes
#pragma unroll
        for (int k = 0; k < 10; ++k) {
            const int off = tid * 10 + k;        // = ic*160 + oc*10 + r
            const int ic  = off / 160;
            const int rem = off - ic * 160;
            const int oc  = rem / 10;
            const int r   = rem - oc * 10;
            ws_[r * 640 + oc * 40 + ic] = f2bf(__expf(wv[k]));
        }
        // ws pad slots 16..31 for all 160 (r,oc)
        if (tid < 160) {
            const int r = tid >> 4, oc = tid & 15;
            uint4* p = reinterpret_cast<uint4*>(&ws_[r * 640 + oc * 40 + 16]);
            const uint4 z = make_uint4(0u, 0u, 0u, 0u);
            p[0] = z; p[1] = z;
        }
    }
    __syncthreads();

    // ---- phase 2: lcs (160 thr) + MFMAs (all 4 waves) ------------------------
    if (tid < 160) {
        const int oc = tid / 10, r = tid - (tid / 10) * 10;
        const unsigned short* p = &ws_[r * 640 + oc * 40];
        float s = 0.f;
#pragma unroll
        for (int ic = 0; ic < 16; ++ic)
            s += __uint_as_float(((unsigned)p[ic]) << 16);
        lcs[oc * 10 + r] = __logf(s);
    }

    const int mt = tid >> 6;             // wave id = m-tile 0..3 (n0 = 16*mt)
    const int l  = tid & 63;
    const int lm = l & 15;               // A row within tile / B col (oc)
    const int kg = l >> 4;               // k-slot group 0..3

    const int abase = (mt * 16 + lm) * 328 + kg * 8;
    const int bbase = lm * 40 + kg * 8;

    f32x4 acc[10];
    const f32x4 zero = {0.f, 0.f, 0.f, 0.f};
#pragma unroll
    for (int r = 0; r < 10; ++r) {
        bf16x8 a = *reinterpret_cast<const bf16x8*>(&es[abase + r * 32]);
        bf16x8 b = *reinterpret_cast<const bf16x8*>(&ws_[r * 640 + bbase]);
        acc[r] = __builtin_amdgcn_mfma_f32_16x16x32_bf16(a, b, zero, 0, 0, 0);
    }
    __syncthreads();   // lcs visible

    // ---- phase 3: epilogue, direct coalesced stores --------------------------
    // C layout (m89, v13-verified): col = lane&15 (=oc), row = kg*4 + j
    float lc[10];
#pragma unroll
    for (int r = 0; r < 10; ++r) lc[r] = lcs[lm * 10 + r];

#pragma unroll
    for (int j = 0; j < 4; ++j) {
        const int n = mt * 16 + kg * 4 + j;
        float* og = out + ((nb + n) * 256 + d) * 160 + lm * 10;
#pragma unroll
        for (int h = 0; h < 5; ++h) {
            float2 o;
            o.x = __logf(acc[2 * h][j])     - lc[2 * h];
            o.y = __logf(acc[2 * h + 1][j]) - lc[2 * h + 1];
            *reinterpret_cast<float2*>(og + 2 * h) = o;
        }
    }
}

extern "C" void kernel_launch(void* const* d_in, const int* in_sizes, int n_in,
                              void* d_out, int out_size, void* d_ws, size_t ws_size,
                              hipStream_t stream) {
    const float* x = (const float*)d_in[0];
    const float* w = (const float*)d_in[1];
    float* out = (float*)d_out;

    // 512 blocks: d = bid&255, n-half = bid>>8; 2 blocks/CU
    fused_mfma_kernel<<<512, 256, 0, stream>>>(x, w, out);
}